// Round 9
// baseline (207.517 us; speedup 1.0000x reference)
//
#include <hip/hip_runtime.h>

// GCN 3-layer + MLP head. Round-9 changes vs round-8 (199us):
//  - k_agg restructured for wide gathers: 16 lanes x uint4 per row, wave
//    processes 4 edges per load instruction (grp=lane>>4 picks the edge,
//    sl=lane&15 picks the 16B slice), unroll x2 -> 8 edges in flight/wave.
//    Cross-group reduce: 2 rounds of __shfl_xor(16/32) on acc[8] per node.
//    (Round-8 issued one 4B load/lane/edge -> issue-rate limited.)
//  - k_scan2 dropped: scatter/finalize locally scan blk[196] in LDS.
// Everything else identical to round 8 (MFMA bf16 GEMMs, counting sort,
// weights at 4MiB+64KB clear of csr).
// Math: h_i = relu(dis_i*( sum_{e:dst=i} dis_src*g_src + dis_i*g_i )+b),
// g = h@W bf16; fp32 accumulation everywhere.

#define DHID 128
#define NBUK 256   // dst buckets
#define NBLK 196   // edge-chunk blocks (NBUK*NBLK = 50176 scan elements)

typedef __attribute__((ext_vector_type(8))) short bf16x8;
typedef __attribute__((ext_vector_type(4))) float f32x4;

static __device__ __forceinline__ unsigned short f2bf(float f) {
  unsigned int u = __float_as_uint(f);
  u += 0x7fffu + ((u >> 16) & 1u);  // round-to-nearest-even
  return (unsigned short)(u >> 16);
}
static __device__ __forceinline__ float bf_lo(unsigned int v) {
  return __uint_as_float(v << 16);
}
static __device__ __forceinline__ float bf_hi(unsigned int v) {
  return __uint_as_float(v & 0xffff0000u);
}
// acc[k] += s * row8[k], row8 = 8 bf16 packed in a uint4
static __device__ __forceinline__ void fma8(float* acc, uint4 v, float s) {
  acc[0] = fmaf(s, bf_lo(v.x), acc[0]);
  acc[1] = fmaf(s, bf_hi(v.x), acc[1]);
  acc[2] = fmaf(s, bf_lo(v.y), acc[2]);
  acc[3] = fmaf(s, bf_hi(v.y), acc[3]);
  acc[4] = fmaf(s, bf_lo(v.z), acc[4]);
  acc[5] = fmaf(s, bf_hi(v.z), acc[5]);
  acc[6] = fmaf(s, bf_lo(v.w), acc[6]);
  acc[7] = fmaf(s, bf_hi(v.w), acc[7]);
}

// ---------------- weight prep: fp32 [K=128][N] -> bf16 Wt[N][128] ----------
__global__ __launch_bounds__(256) void k_prep(const float* __restrict__ W1,
                                              const float* __restrict__ W2,
                                              const float* __restrict__ W3,
                                              const float* __restrict__ Wo1,
                                              const float* __restrict__ Wo2,
                                              unsigned short* __restrict__ W1t,
                                              unsigned short* __restrict__ W2t,
                                              unsigned short* __restrict__ W3t,
                                              unsigned short* __restrict__ Wo1t,
                                              unsigned short* __restrict__ Wo2t) {
  int b = blockIdx.x;  // 40 blocks: 8 per weight
  int wi = b >> 3, part = b & 7;
  const float* src;
  unsigned short* dst;
  int N;
  switch (wi) {
    case 0: src = W1; dst = W1t; N = 128; break;
    case 1: src = W2; dst = W2t; N = 128; break;
    case 2: src = W3; dst = W3t; N = 128; break;
    case 3: src = Wo1; dst = Wo1t; N = 128; break;
    default: src = Wo2; dst = Wo2t; N = 64; break;
  }
  int cpp = N >> 3;  // cols per part
  int c0 = part * cpp;
  for (int idx = threadIdx.x; idx < cpp * 128; idx += 256) {
    int c = c0 + (idx >> 7);
    int k = idx & 127;
    dst[c * 128 + k] = f2bf(src[(size_t)k * N + c]);  // write coalesced
  }
}

// ---------------- MFMA GEMM body: [64,128] @ Wt^T -> out -------------------
// OMODE 0: bf16 out, no bias; 1: bf16 out + bias; 2: fp32 out + bias (N=64)
template <int NCOLS, int INF32, int OMODE>
__device__ __forceinline__ void mgemm_body(const void* __restrict__ Hsrc,
                                           const unsigned short* __restrict__ Wt,
                                           const float* __restrict__ bias,
                                           void* __restrict__ out, int M,
                                           int row0) {
  __shared__ unsigned short As[64][136];      // +8 pad: 272B stride
  __shared__ unsigned short Ws[NCOLS][136];
  int tid = threadIdx.x;

  // stage A tile (64 rows x 128 bf16)
  {
    int row = tid >> 2;   // 0..63
    int seg = tid & 3;    // 32 shorts each
    int gr = row0 + row;
    if (INF32) {
      const float4* H4 = (const float4*)Hsrc;  // row = 32 float4
#pragma unroll
      for (int i = 0; i < 8; i++) {
        float4 v = (gr < M) ? H4[(size_t)gr * 32 + seg * 8 + i]
                            : make_float4(0.f, 0.f, 0.f, 0.f);
        ushort4 o;
        o.x = f2bf(v.x); o.y = f2bf(v.y); o.z = f2bf(v.z); o.w = f2bf(v.w);
        *(ushort4*)&As[row][seg * 32 + i * 4] = o;
      }
    } else {
      const uint4* H4 = (const uint4*)Hsrc;  // row = 16 uint4 (128 bf16)
#pragma unroll
      for (int i = 0; i < 4; i++) {
        uint4 v = (gr < M) ? H4[(size_t)gr * 16 + seg * 4 + i]
                           : make_uint4(0u, 0u, 0u, 0u);
        *(uint4*)&As[row][seg * 32 + i * 8] = v;
      }
    }
  }
  // stage Wt (NCOLS x 128 bf16 = NCOLS*16 uint4)
  {
    const uint4* Wt4 = (const uint4*)Wt;
    for (int idx = tid; idx < NCOLS * 16; idx += 256) {
      int c = idx >> 4, kk = idx & 15;
      *(uint4*)&Ws[c][kk * 8] = Wt4[idx];
    }
  }
  __syncthreads();

  int l = tid & 63;
  int w = tid >> 6;        // wave 0..3 -> rows w*16..w*16+15
  int mrow = l & 15;
  int kch = (l >> 4) * 8;

  f32x4 acc[NCOLS / 16];
#pragma unroll
  for (int c = 0; c < NCOLS / 16; c++) acc[c] = (f32x4){0.f, 0.f, 0.f, 0.f};

#pragma unroll
  for (int kk = 0; kk < 4; kk++) {
    bf16x8 a = *(const bf16x8*)&As[w * 16 + mrow][kk * 32 + kch];
#pragma unroll
    for (int c = 0; c < NCOLS / 16; c++) {
      bf16x8 b = *(const bf16x8*)&Ws[c * 16 + mrow][kk * 32 + kch];
      acc[c] = __builtin_amdgcn_mfma_f32_16x16x32_bf16(a, b, acc[c], 0, 0, 0);
    }
  }

  int rbase = row0 + w * 16 + (l >> 4) * 4;
#pragma unroll
  for (int c = 0; c < NCOLS / 16; c++) {
    int col = c * 16 + mrow;
    float bv = (OMODE != 0) ? bias[col] : 0.f;
#pragma unroll
    for (int r = 0; r < 4; r++) {
      int gr = rbase + r;
      if (gr < M) {
        float v = acc[c][r] + bv;
        if (OMODE == 2)
          ((float*)out)[(size_t)gr * NCOLS + col] = v;
        else
          ((unsigned short*)out)[(size_t)gr * 128 + col] = f2bf(v);
      }
    }
  }
}

template <int NCOLS, int INF32, int OMODE>
__global__ __launch_bounds__(256) void k_mgemm(const void* __restrict__ H,
                                               const unsigned short* __restrict__ Wt,
                                               const float* __restrict__ bias,
                                               void* __restrict__ out, int M) {
  mgemm_body<NCOLS, INF32, OMODE>(H, Wt, bias, out, M, (int)blockIdx.x * 64);
}

// layer-1 MFMA GEMM (x fp32 -> gA bf16) fused with sort pass 1 (histogram).
__global__ __launch_bounds__(256) void k_gemm1_hist(const float* __restrict__ x,
                                                    const unsigned short* __restrict__ W1t,
                                                    void* __restrict__ out, int M,
                                                    int nG, const int* __restrict__ ei,
                                                    int E, int EPB, int NPB,
                                                    int* __restrict__ Hist) {
  __shared__ int hs[NBUK];
  if ((int)blockIdx.x >= nG) {
    int tid = threadIdx.x;
    int j = (int)blockIdx.x - nG;
    hs[tid] = 0;
    __syncthreads();
    int e0 = j * EPB;
    int e1 = min(e0 + EPB, E);
    for (int e = e0 + tid; e < e1; e += 256) {
      int d = ei[E + e];
      atomicAdd(&hs[d / NPB], 1);
    }
    __syncthreads();
    Hist[tid * NBLK + j] = hs[tid];
    return;
  }
  mgemm_body<128, 1, 0>(x, W1t, nullptr, out, M, (int)blockIdx.x * 64);
}

// ---------------- scan (pass 1 only; blk scanned locally by consumers) -----

__global__ __launch_bounds__(256) void k_scan1(const int* __restrict__ in,
                                               int* __restrict__ out,
                                               int* __restrict__ blk, int Mtot) {
  __shared__ int s[256];
  int tid = threadIdx.x;
  int i = blockIdx.x * 256 + tid;
  int v = (i < Mtot) ? in[i] : 0;
  s[tid] = v;
  __syncthreads();
  for (int off = 1; off < 256; off <<= 1) {
    int t = (tid >= off) ? s[tid - off] : 0;
    __syncthreads();
    s[tid] += t;
    __syncthreads();
  }
  if (i < Mtot) out[i] = s[tid] - v;  // exclusive within block
  if (tid == 255) blk[blockIdx.x] = s[255];
}

// local exclusive scan of blk[0..NBLK) into sblk (256 threads, NBLK<=256)
static __device__ __forceinline__ void scan_blk(const int* __restrict__ blk,
                                                int* sblk, int tid) {
  int bv = (tid < NBLK) ? blk[tid] : 0;
  sblk[tid] = bv;
  __syncthreads();
  for (int off = 1; off < 256; off <<= 1) {
    int t = (tid >= off) ? sblk[tid - off] : 0;
    __syncthreads();
    sblk[tid] += t;
    __syncthreads();
  }
  int excl = sblk[tid] - bv;
  __syncthreads();
  sblk[tid] = excl;
  __syncthreads();
}

// sort pass 2: bucket-grouped scatter.
__global__ __launch_bounds__(256) void k_scatter(const int* __restrict__ ei, int E,
                                                 int EPB, int NPB,
                                                 const int* __restrict__ S,
                                                 const int* __restrict__ blk,
                                                 int2* __restrict__ sorted) {
  __shared__ int run[NBUK];
  __shared__ int sblk[256];
  int tid = threadIdx.x;
  int j = blockIdx.x;
  scan_blk(blk, sblk, tid);
  int idx = tid * NBLK + j;
  run[tid] = S[idx] + sblk[idx >> 8];
  __syncthreads();
  int e0 = j * EPB;
  int e1 = min(e0 + EPB, E);
  for (int e = e0 + tid; e < e1; e += 256) {
    int s = ei[e];
    int d = ei[E + e];
    int slot = atomicAdd(&run[d / NPB], 1);
    sorted[slot] = make_int2(s, d);
  }
}

// sort pass 3: per-bucket finalize -> rp, dis, csr.
__global__ __launch_bounds__(256) void k_finalize(const int2* __restrict__ sorted,
                                                  const int* __restrict__ S,
                                                  const int* __restrict__ blk,
                                                  int E, int M, int NPB,
                                                  int* __restrict__ rp,
                                                  float* __restrict__ dis,
                                                  int* __restrict__ csr) {
  __shared__ int cnt[256];
  __shared__ int sc[256];
  __shared__ int sblk[256];
  int b = blockIdx.x;
  int tid = threadIdx.x;
  scan_blk(blk, sblk, tid);
  int node0 = b * NPB;
  int i0 = b * NBLK;
  int start = S[i0] + sblk[i0 >> 8];
  int end;
  if (b == NBUK - 1) end = E;
  else {
    int i1 = i0 + NBLK;
    end = S[i1] + sblk[i1 >> 8];
  }
  cnt[tid] = 0;
  __syncthreads();
  for (int i = start + tid; i < end; i += 256) {
    atomicAdd(&cnt[sorted[i].y - node0], 1);
  }
  __syncthreads();
  int v = cnt[tid];
  sc[tid] = v;
  __syncthreads();
  for (int off = 1; off < 256; off <<= 1) {
    int t = (tid >= off) ? sc[tid - off] : 0;
    __syncthreads();
    sc[tid] += t;
    __syncthreads();
  }
  int lrp = sc[tid] - v;
  int node = node0 + tid;
  if (tid < NPB && node < M) {
    rp[node] = start + lrp;
    dis[node] = rsqrtf((float)v + 1.0f);
  }
  if (b == NBUK - 1 && tid == 0) rp[M] = E;
  __syncthreads();
  cnt[tid] = lrp;
  __syncthreads();
  for (int i = start + tid; i < end; i += 256) {
    int2 p = sorted[i];
    int slot = atomicAdd(&cnt[p.y - node0], 1);
    csr[start + slot] = p.x;
  }
}

// ---------------- Aggregation: one wave per node, wide uint4 gather --------
// h_out[i] = relu( dis_i*( sum_{e:dst=i} dis_src*g_src + dis_i*g_i ) + b )
// Lane = (grp=l>>4, sl=l&15): grp picks the edge (4 edges per wave-load),
// sl picks the 16B slice of the 256B row. acc[8] fp32 per lane; 2-round
// shfl_xor cross-group reduce per node; grp0 packs+stores uint4.
__global__ __launch_bounds__(256) void k_agg(const unsigned short* __restrict__ g,
                                             const int* __restrict__ csr,
                                             const int* __restrict__ rp,
                                             const float* __restrict__ dis,
                                             const float* __restrict__ bias,
                                             unsigned short* __restrict__ outh,
                                             int M) {
  int wid = (int)((blockIdx.x * 256 + threadIdx.x) >> 6);  // node id
  int lane = threadIdx.x & 63;
  if (wid >= M) return;
  int grp = lane >> 4;
  int sl = lane & 15;
  const uint4* g4 = (const uint4*)g;  // row = 16 uint4 (128 bf16)
  float di = dis[wid];

  float acc[8];
#pragma unroll
  for (int k = 0; k < 8; k++) acc[k] = 0.f;

  // self term (counted once, by grp 0; all lanes load -> warms row in cache)
  {
    uint4 v = g4[(size_t)wid * 16 + sl];
    if (grp == 0) fma8(acc, v, di);
  }

  int start = rp[wid], end = rp[wid + 1];
  for (int base = start; base < end; base += 8) {
    int e0 = base + grp;
    int e1 = e0 + 4;
    int idx0 = wid, idx1 = wid;
    float s0 = 0.f, s1 = 0.f;
    if (e0 < end) {
      idx0 = csr[e0];
      s0 = dis[idx0];
    }
    if (e1 < end) {
      idx1 = csr[e1];
      s1 = dis[idx1];
    }
    uint4 v0 = g4[(size_t)idx0 * 16 + sl];
    uint4 v1 = g4[(size_t)idx1 * 16 + sl];
    fma8(acc, v0, s0);
    fma8(acc, v1, s1);
  }

  // reduce across the 4 edge-groups (lane bits 4,5)
#pragma unroll
  for (int k = 0; k < 8; k++) {
    acc[k] += __shfl_xor(acc[k], 16, 64);
    acc[k] += __shfl_xor(acc[k], 32, 64);
  }

  if (grp == 0) {
    const float4* b4 = (const float4*)bias;
    float4 ba = b4[sl * 2];
    float4 bb = b4[sl * 2 + 1];
    float r0 = fmaxf(fmaf(di, acc[0], ba.x), 0.f);
    float r1 = fmaxf(fmaf(di, acc[1], ba.y), 0.f);
    float r2 = fmaxf(fmaf(di, acc[2], ba.z), 0.f);
    float r3 = fmaxf(fmaf(di, acc[3], ba.w), 0.f);
    float r4 = fmaxf(fmaf(di, acc[4], bb.x), 0.f);
    float r5 = fmaxf(fmaf(di, acc[5], bb.y), 0.f);
    float r6 = fmaxf(fmaf(di, acc[6], bb.z), 0.f);
    float r7 = fmaxf(fmaf(di, acc[7], bb.w), 0.f);
    uint4 o;
    o.x = (unsigned int)f2bf(r0) | ((unsigned int)f2bf(r1) << 16);
    o.y = (unsigned int)f2bf(r2) | ((unsigned int)f2bf(r3) << 16);
    o.z = (unsigned int)f2bf(r4) | ((unsigned int)f2bf(r5) << 16);
    o.w = (unsigned int)f2bf(r6) | ((unsigned int)f2bf(r7) << 16);
    ((uint4*)outh)[(size_t)wid * 16 + sl] = o;
  }
}

// ---------------- launch ----------------

extern "C" void kernel_launch(void* const* d_in, const int* in_sizes, int n_in,
                              void* d_out, int out_size, void* d_ws, size_t ws_size,
                              hipStream_t stream) {
  const float* x = (const float*)d_in[0];
  const int* ei = (const int*)d_in[1];
  const float* W1 = (const float*)d_in[2];
  const float* b1 = (const float*)d_in[3];
  const float* W2 = (const float*)d_in[4];
  const float* b2 = (const float*)d_in[5];
  const float* W3 = (const float*)d_in[6];
  const float* b3 = (const float*)d_in[7];
  const float* Wo1 = (const float*)d_in[8];
  const float* bo1 = (const float*)d_in[9];
  const float* Wo2 = (const float*)d_in[10];
  const float* bo2 = (const float*)d_in[11];
  float* out = (float*)d_out;

  int M = in_sizes[0] / DHID;  // 50000
  int E = in_sizes[1] / 2;     // 800000

  int NPB = (M + NBUK - 1) / NBUK;  // nodes per bucket (196)
  int EPB = (E + NBLK - 1) / NBLK;  // edges per sort block
  int SCN = NBUK * NBLK;            // 50176

  // workspace layout (~54.1 MB peak). Weights at 4MiB+64KB — csr spans
  // [5MiB, 8.45MiB) and must NOT touch them (round-7 NaN bug).
  char* ws = (char*)d_ws;
  float* dis = (float*)(ws + 0);                        // M floats (200KB)
  int* rp = (int*)(ws + (1ull << 20));                  // M+1 ints
  int* Hist = (int*)(ws + (2ull << 20));                // SCN ints (200KB)
  int* S = (int*)(ws + (3ull << 20));                   // SCN ints
  int* blk = (int*)(ws + (4ull << 20));                 // <=256 ints (1KB)
  unsigned short* W1t = (unsigned short*)(ws + (4ull << 20) + 65536 + 0 * 32768);
  unsigned short* W2t = (unsigned short*)(ws + (4ull << 20) + 65536 + 1 * 32768);
  unsigned short* W3t = (unsigned short*)(ws + (4ull << 20) + 65536 + 2 * 32768);
  unsigned short* Wo1t = (unsigned short*)(ws + (4ull << 20) + 65536 + 3 * 32768);
  unsigned short* Wo2t = (unsigned short*)(ws + (4ull << 20) + 65536 + 4 * 32768);
  // weights end at 4MiB+64KB+160KB = 4,423,680 < 5MiB ✓
  int* csr = (int*)(ws + (5ull << 20));                 // E ints: [5MiB, 8.45MiB)
  unsigned short* gA = (unsigned short*)(ws + (9ull << 20));   // M*128 bf16
  unsigned short* gB = (unsigned short*)(ws + (22ull << 20));  // M*128 bf16
  unsigned short* hb = (unsigned short*)(ws + (35ull << 20));  // M*128 bf16
  int2* sorted = (int2*)(ws + (48ull << 20));           // E int2 (6.4 MB)

  int gG = (M + 63) / 64;  // 782
  int gA4 = (M + 3) / 4;   // agg: 4 waves/block, wave per node

  // weight prep (bf16 transpose), then layer-1 GEMM fused with sort pass 1
  k_prep<<<40, 256, 0, stream>>>(W1, W2, W3, Wo1, Wo2, W1t, W2t, W3t, Wo1t, Wo2t);
  k_gemm1_hist<<<gG + NBLK, 256, 0, stream>>>(x, W1t, gA, M, gG, ei, E, EPB, NPB, Hist);
  // scan Hist (block totals scanned locally by scatter/finalize)
  k_scan1<<<NBLK, 256, 0, stream>>>(Hist, S, blk, SCN);
  // sort pass 2 + 3
  k_scatter<<<NBLK, 256, 0, stream>>>(ei, E, EPB, NPB, S, blk, sorted);
  k_finalize<<<NBUK, 256, 0, stream>>>(sorted, S, blk, E, M, NPB, rp, dis, csr);

  // GCN layers (agg -> MFMA gemm)
  k_agg<<<gA4, 256, 0, stream>>>(gA, csr, rp, dis, b1, hb, M);
  k_mgemm<128, 0, 0><<<gG, 256, 0, stream>>>(hb, W2t, nullptr, gB, M);
  k_agg<<<gA4, 256, 0, stream>>>(gB, csr, rp, dis, b2, hb, M);
  k_mgemm<128, 0, 0><<<gG, 256, 0, stream>>>(hb, W3t, nullptr, gA, M);
  k_agg<<<gA4, 256, 0, stream>>>(gA, csr, rp, dis, b3, hb, M);
  // MLP head: t = hb@Wo1+bo1 (bf16, reuse gB), out = t@Wo2+bo2 (fp32)
  k_mgemm<128, 0, 1><<<gG, 256, 0, stream>>>(hb, Wo1t, bo1, gB, M);
  k_mgemm<64, 0, 2><<<gG, 256, 0, stream>>>(gB, Wo2t, bo2, out, M);
}

// Round 10
// 202.256 us; speedup vs baseline: 1.0260x; 1.0260x over previous
//
#include <hip/hip_runtime.h>

// GCN 3-layer + MLP head. Round-10 (base = round-8's 199.4us; round-9's wide
// gather was a confirmed-null: agg is L2/L3-BW-bound at ~7TB/s):
//  - k_agg reverted to round-8 one-uint-per-lane form, now templated:
//    GDIS=1 (layer 1) gathers dis[src] per edge; GDIS=0 (layers 2/3) reads
//    pre-scaled g (dis folded into the producing GEMM epilogue, OMODE=3).
//  - MLP head GEMMs fused: t = h@Wo1+bo1 lives in LDS (bf16), then
//    out = t@Wo2+bo2. Saves 25.6MB of t round-trip + one launch.
//  - keeps round-9's scan_blk localization (no k_scan2 launch).
// Math: h_i = relu(dis_i*( sum_{e:dst=i} [dis_src*]g_src + self )+b),
// fp32 accumulation everywhere; g,h,W in bf16.

#define DHID 128
#define NBUK 256   // dst buckets
#define NBLK 196   // edge-chunk blocks (NBUK*NBLK = 50176 scan elements)

typedef __attribute__((ext_vector_type(8))) short bf16x8;
typedef __attribute__((ext_vector_type(4))) float f32x4;

static __device__ __forceinline__ unsigned short f2bf(float f) {
  unsigned int u = __float_as_uint(f);
  u += 0x7fffu + ((u >> 16) & 1u);  // round-to-nearest-even
  return (unsigned short)(u >> 16);
}
static __device__ __forceinline__ float bf_lo(unsigned int v) {
  return __uint_as_float(v << 16);
}
static __device__ __forceinline__ float bf_hi(unsigned int v) {
  return __uint_as_float(v & 0xffff0000u);
}

// ---------------- weight prep: fp32 [K=128][N] -> bf16 Wt[N][128] ----------
__global__ __launch_bounds__(256) void k_prep(const float* __restrict__ W1,
                                              const float* __restrict__ W2,
                                              const float* __restrict__ W3,
                                              const float* __restrict__ Wo1,
                                              const float* __restrict__ Wo2,
                                              unsigned short* __restrict__ W1t,
                                              unsigned short* __restrict__ W2t,
                                              unsigned short* __restrict__ W3t,
                                              unsigned short* __restrict__ Wo1t,
                                              unsigned short* __restrict__ Wo2t) {
  int b = blockIdx.x;  // 40 blocks: 8 per weight
  int wi = b >> 3, part = b & 7;
  const float* src;
  unsigned short* dst;
  int N;
  switch (wi) {
    case 0: src = W1; dst = W1t; N = 128; break;
    case 1: src = W2; dst = W2t; N = 128; break;
    case 2: src = W3; dst = W3t; N = 128; break;
    case 3: src = Wo1; dst = Wo1t; N = 128; break;
    default: src = Wo2; dst = Wo2t; N = 64; break;
  }
  int cpp = N >> 3;  // cols per part
  int c0 = part * cpp;
  for (int idx = threadIdx.x; idx < cpp * 128; idx += 256) {
    int c = c0 + (idx >> 7);
    int k = idx & 127;
    dst[c * 128 + k] = f2bf(src[(size_t)k * N + c]);  // write coalesced
  }
}

// ---------------- MFMA GEMM body: [64,128] @ Wt^T -> out -------------------
// OMODE 0: bf16 out; 1: bf16 out + bias; 2: fp32 out + bias; 3: bf16 dis-scaled
template <int NCOLS, int INF32, int OMODE>
__device__ __forceinline__ void mgemm_body(const void* __restrict__ Hsrc,
                                           const unsigned short* __restrict__ Wt,
                                           const float* __restrict__ bias,
                                           const float* __restrict__ dis,
                                           void* __restrict__ out, int M,
                                           int row0) {
  __shared__ unsigned short As[64][136];      // +8 pad: 272B stride
  __shared__ unsigned short Ws[NCOLS][136];
  int tid = threadIdx.x;

  // stage A tile (64 rows x 128 bf16)
  {
    int row = tid >> 2;   // 0..63
    int seg = tid & 3;    // 32 shorts each
    int gr = row0 + row;
    if (INF32) {
      const float4* H4 = (const float4*)Hsrc;  // row = 32 float4
#pragma unroll
      for (int i = 0; i < 8; i++) {
        float4 v = (gr < M) ? H4[(size_t)gr * 32 + seg * 8 + i]
                            : make_float4(0.f, 0.f, 0.f, 0.f);
        ushort4 o;
        o.x = f2bf(v.x); o.y = f2bf(v.y); o.z = f2bf(v.z); o.w = f2bf(v.w);
        *(ushort4*)&As[row][seg * 32 + i * 4] = o;
      }
    } else {
      const uint4* H4 = (const uint4*)Hsrc;  // row = 16 uint4 (128 bf16)
#pragma unroll
      for (int i = 0; i < 4; i++) {
        uint4 v = (gr < M) ? H4[(size_t)gr * 16 + seg * 4 + i]
                           : make_uint4(0u, 0u, 0u, 0u);
        *(uint4*)&As[row][seg * 32 + i * 8] = v;
      }
    }
  }
  // stage Wt (NCOLS x 128 bf16 = NCOLS*16 uint4)
  {
    const uint4* Wt4 = (const uint4*)Wt;
    for (int idx = tid; idx < NCOLS * 16; idx += 256) {
      int c = idx >> 4, kk = idx & 15;
      *(uint4*)&Ws[c][kk * 8] = Wt4[idx];
    }
  }
  __syncthreads();

  int l = tid & 63;
  int w = tid >> 6;        // wave 0..3 -> rows w*16..w*16+15
  int mrow = l & 15;
  int kch = (l >> 4) * 8;

  f32x4 acc[NCOLS / 16];
#pragma unroll
  for (int c = 0; c < NCOLS / 16; c++) acc[c] = (f32x4){0.f, 0.f, 0.f, 0.f};

#pragma unroll
  for (int kk = 0; kk < 4; kk++) {
    bf16x8 a = *(const bf16x8*)&As[w * 16 + mrow][kk * 32 + kch];
#pragma unroll
    for (int c = 0; c < NCOLS / 16; c++) {
      bf16x8 b = *(const bf16x8*)&Ws[c * 16 + mrow][kk * 32 + kch];
      acc[c] = __builtin_amdgcn_mfma_f32_16x16x32_bf16(a, b, acc[c], 0, 0, 0);
    }
  }

  int rbase = row0 + w * 16 + (l >> 4) * 4;
#pragma unroll
  for (int c = 0; c < NCOLS / 16; c++) {
    int col = c * 16 + mrow;
    float bv = (OMODE == 1 || OMODE == 2) ? bias[col] : 0.f;
#pragma unroll
    for (int r = 0; r < 4; r++) {
      int gr = rbase + r;
      if (gr < M) {
        float v = acc[c][r] + bv;
        if (OMODE == 3) v = acc[c][r] * dis[gr];
        if (OMODE == 2)
          ((float*)out)[(size_t)gr * NCOLS + col] = v;
        else
          ((unsigned short*)out)[(size_t)gr * 128 + col] = f2bf(v);
      }
    }
  }
}

template <int NCOLS, int INF32, int OMODE>
__global__ __launch_bounds__(256) void k_mgemm(const void* __restrict__ H,
                                               const unsigned short* __restrict__ Wt,
                                               const float* __restrict__ bias,
                                               const float* __restrict__ dis,
                                               void* __restrict__ out, int M) {
  mgemm_body<NCOLS, INF32, OMODE>(H, Wt, bias, dis, out, M, (int)blockIdx.x * 64);
}

// ---------------- fused MLP head: out = (h@Wo1+bo1)@Wo2+bo2 ----------------
__global__ __launch_bounds__(256) void k_mgemm2(const unsigned short* __restrict__ hb,
                                                const unsigned short* __restrict__ Wo1t,
                                                const float* __restrict__ bo1,
                                                const unsigned short* __restrict__ Wo2t,
                                                const float* __restrict__ bo2,
                                                float* __restrict__ out, int M) {
  __shared__ unsigned short As[64][136];   // h tile, then t tile (bf16)
  __shared__ unsigned short Ws[128][136];  // Wo1t, rows 0..63 reused for Wo2t
  int tid = threadIdx.x;
  int row0 = (int)blockIdx.x * 64;

  // stage h tile
  {
    int row = tid >> 2, seg = tid & 3;
    int gr = row0 + row;
    const uint4* H4 = (const uint4*)hb;
#pragma unroll
    for (int i = 0; i < 4; i++) {
      uint4 v = (gr < M) ? H4[(size_t)gr * 16 + seg * 4 + i]
                         : make_uint4(0u, 0u, 0u, 0u);
      *(uint4*)&As[row][seg * 32 + i * 8] = v;
    }
  }
  // stage Wo1t (128 x 128)
  {
    const uint4* Wt4 = (const uint4*)Wo1t;
    for (int idx = tid; idx < 128 * 16; idx += 256) {
      int c = idx >> 4, kk = idx & 15;
      *(uint4*)&Ws[c][kk * 8] = Wt4[idx];
    }
  }
  __syncthreads();

  int l = tid & 63;
  int w = tid >> 6;
  int mrow = l & 15;
  int kch = (l >> 4) * 8;

  // GEMM1: t = h @ Wo1 (+bo1)
  f32x4 acc[8];
#pragma unroll
  for (int c = 0; c < 8; c++) acc[c] = (f32x4){0.f, 0.f, 0.f, 0.f};
#pragma unroll
  for (int kk = 0; kk < 4; kk++) {
    bf16x8 a = *(const bf16x8*)&As[w * 16 + mrow][kk * 32 + kch];
#pragma unroll
    for (int c = 0; c < 8; c++) {
      bf16x8 b = *(const bf16x8*)&Ws[c * 16 + mrow][kk * 32 + kch];
      acc[c] = __builtin_amdgcn_mfma_f32_16x16x32_bf16(a, b, acc[c], 0, 0, 0);
    }
  }
  __syncthreads();  // all As/Ws reads done

  // write t (bf16, +bo1) into As; stage Wo2t into Ws rows 0..63
  {
    int lrbase = w * 16 + (l >> 4) * 4;
#pragma unroll
    for (int c = 0; c < 8; c++) {
      int col = c * 16 + mrow;
      float bv = bo1[col];
#pragma unroll
      for (int r = 0; r < 4; r++)
        As[lrbase + r][col] = f2bf(acc[c][r] + bv);
    }
    const uint4* Wt4 = (const uint4*)Wo2t;
    for (int idx = tid; idx < 64 * 16; idx += 256) {
      int c = idx >> 4, kk = idx & 15;
      *(uint4*)&Ws[c][kk * 8] = Wt4[idx];
    }
  }
  __syncthreads();

  // GEMM2: out = t @ Wo2 + bo2 (fp32, 64 cols)
  f32x4 a2[4];
#pragma unroll
  for (int c = 0; c < 4; c++) a2[c] = (f32x4){0.f, 0.f, 0.f, 0.f};
#pragma unroll
  for (int kk = 0; kk < 4; kk++) {
    bf16x8 a = *(const bf16x8*)&As[w * 16 + mrow][kk * 32 + kch];
#pragma unroll
    for (int c = 0; c < 4; c++) {
      bf16x8 b = *(const bf16x8*)&Ws[c * 16 + mrow][kk * 32 + kch];
      a2[c] = __builtin_amdgcn_mfma_f32_16x16x32_bf16(a, b, a2[c], 0, 0, 0);
    }
  }
  int rbase = row0 + w * 16 + (l >> 4) * 4;
#pragma unroll
  for (int c = 0; c < 4; c++) {
    int col = c * 16 + mrow;
    float bv = bo2[col];
#pragma unroll
    for (int r = 0; r < 4; r++) {
      int gr = rbase + r;
      if (gr < M) out[(size_t)gr * 64 + col] = a2[c][r] + bv;
    }
  }
}

// layer-1 MFMA GEMM (x fp32 -> gA bf16, unscaled) fused with histogram.
__global__ __launch_bounds__(256) void k_gemm1_hist(const float* __restrict__ x,
                                                    const unsigned short* __restrict__ W1t,
                                                    void* __restrict__ out, int M,
                                                    int nG, const int* __restrict__ ei,
                                                    int E, int EPB, int NPB,
                                                    int* __restrict__ Hist) {
  __shared__ int hs[NBUK];
  if ((int)blockIdx.x >= nG) {
    int tid = threadIdx.x;
    int j = (int)blockIdx.x - nG;
    hs[tid] = 0;
    __syncthreads();
    int e0 = j * EPB;
    int e1 = min(e0 + EPB, E);
    for (int e = e0 + tid; e < e1; e += 256) {
      int d = ei[E + e];
      atomicAdd(&hs[d / NPB], 1);
    }
    __syncthreads();
    Hist[tid * NBLK + j] = hs[tid];
    return;
  }
  mgemm_body<128, 1, 0>(x, W1t, nullptr, nullptr, out, M, (int)blockIdx.x * 64);
}

// ---------------- scan (pass 1 only; blk scanned locally by consumers) -----

__global__ __launch_bounds__(256) void k_scan1(const int* __restrict__ in,
                                               int* __restrict__ out,
                                               int* __restrict__ blk, int Mtot) {
  __shared__ int s[256];
  int tid = threadIdx.x;
  int i = blockIdx.x * 256 + tid;
  int v = (i < Mtot) ? in[i] : 0;
  s[tid] = v;
  __syncthreads();
  for (int off = 1; off < 256; off <<= 1) {
    int t = (tid >= off) ? s[tid - off] : 0;
    __syncthreads();
    s[tid] += t;
    __syncthreads();
  }
  if (i < Mtot) out[i] = s[tid] - v;  // exclusive within block
  if (tid == 255) blk[blockIdx.x] = s[255];
}

// local exclusive scan of blk[0..NBLK) into sblk (256 threads, NBLK<=256)
static __device__ __forceinline__ void scan_blk(const int* __restrict__ blk,
                                                int* sblk, int tid) {
  int bv = (tid < NBLK) ? blk[tid] : 0;
  sblk[tid] = bv;
  __syncthreads();
  for (int off = 1; off < 256; off <<= 1) {
    int t = (tid >= off) ? sblk[tid - off] : 0;
    __syncthreads();
    sblk[tid] += t;
    __syncthreads();
  }
  int excl = sblk[tid] - bv;
  __syncthreads();
  sblk[tid] = excl;
  __syncthreads();
}

// sort pass 2: bucket-grouped scatter.
__global__ __launch_bounds__(256) void k_scatter(const int* __restrict__ ei, int E,
                                                 int EPB, int NPB,
                                                 const int* __restrict__ S,
                                                 const int* __restrict__ blk,
                                                 int2* __restrict__ sorted) {
  __shared__ int run[NBUK];
  __shared__ int sblk[256];
  int tid = threadIdx.x;
  int j = blockIdx.x;
  scan_blk(blk, sblk, tid);
  int idx = tid * NBLK + j;
  run[tid] = S[idx] + sblk[idx >> 8];
  __syncthreads();
  int e0 = j * EPB;
  int e1 = min(e0 + EPB, E);
  for (int e = e0 + tid; e < e1; e += 256) {
    int s = ei[e];
    int d = ei[E + e];
    int slot = atomicAdd(&run[d / NPB], 1);
    sorted[slot] = make_int2(s, d);
  }
}

// sort pass 3: per-bucket finalize -> rp, dis, csr.
__global__ __launch_bounds__(256) void k_finalize(const int2* __restrict__ sorted,
                                                  const int* __restrict__ S,
                                                  const int* __restrict__ blk,
                                                  int E, int M, int NPB,
                                                  int* __restrict__ rp,
                                                  float* __restrict__ dis,
                                                  int* __restrict__ csr) {
  __shared__ int cnt[256];
  __shared__ int sc[256];
  __shared__ int sblk[256];
  int b = blockIdx.x;
  int tid = threadIdx.x;
  scan_blk(blk, sblk, tid);
  int node0 = b * NPB;
  int i0 = b * NBLK;
  int start = S[i0] + sblk[i0 >> 8];
  int end;
  if (b == NBUK - 1) end = E;
  else {
    int i1 = i0 + NBLK;
    end = S[i1] + sblk[i1 >> 8];
  }
  cnt[tid] = 0;
  __syncthreads();
  for (int i = start + tid; i < end; i += 256) {
    atomicAdd(&cnt[sorted[i].y - node0], 1);
  }
  __syncthreads();
  int v = cnt[tid];
  sc[tid] = v;
  __syncthreads();
  for (int off = 1; off < 256; off <<= 1) {
    int t = (tid >= off) ? sc[tid - off] : 0;
    __syncthreads();
    sc[tid] += t;
    __syncthreads();
  }
  int lrp = sc[tid] - v;
  int node = node0 + tid;
  if (tid < NPB && node < M) {
    rp[node] = start + lrp;
    dis[node] = rsqrtf((float)v + 1.0f);
  }
  if (b == NBUK - 1 && tid == 0) rp[M] = E;
  __syncthreads();
  cnt[tid] = lrp;
  __syncthreads();
  for (int i = start + tid; i < end; i += 256) {
    int2 p = sorted[i];
    int slot = atomicAdd(&cnt[p.y - node0], 1);
    csr[start + slot] = p.x;
  }
}

// ---------------- Aggregation: one wave per node (round-8 form) ------------
// GDIS=1: h = relu(di*(sum dis_src*g_src + di*g_i)+b)   [layer 1, unscaled g]
// GDIS=0: h = relu(di*(sum g_src + g_i)+b)              [g pre-scaled by dis]
template <int GDIS>
__global__ __launch_bounds__(256) void k_agg(const unsigned short* __restrict__ g,
                                             const int* __restrict__ csr,
                                             const int* __restrict__ rp,
                                             const float* __restrict__ dis,
                                             const float* __restrict__ bias,
                                             unsigned short* __restrict__ outh,
                                             int M) {
  int wid = (int)((blockIdx.x * 256 + threadIdx.x) >> 6);  // node id
  int lane = threadIdx.x & 63;
  if (wid >= M) return;
  const unsigned int* g1 = (const unsigned int*)g;  // 2 bf16 per uint
  float di = dis[wid];
  unsigned int self = g1[(size_t)wid * 64 + lane];
  float ax, ay;
  if (GDIS) {
    ax = di * bf_lo(self);
    ay = di * bf_hi(self);
  } else {
    ax = bf_lo(self);
    ay = bf_hi(self);
  }
  int start = rp[wid], end = rp[wid + 1];
  for (int base = start; base < end; base += 64) {
    int n = end - base;
    if (n > 64) n = 64;
    int idx = 0;
    float dsv = 0.f;
    if (lane < n) {
      idx = csr[base + lane];
      if (GDIS) dsv = dis[idx];
    }
    int jx = 0;
    for (; jx + 4 <= n; jx += 4) {
      int s0 = __shfl(idx, jx, 64);
      int s1 = __shfl(idx, jx + 1, 64);
      int s2 = __shfl(idx, jx + 2, 64);
      int s3 = __shfl(idx, jx + 3, 64);
      unsigned int v0 = g1[(size_t)s0 * 64 + lane];
      unsigned int v1 = g1[(size_t)s1 * 64 + lane];
      unsigned int v2 = g1[(size_t)s2 * 64 + lane];
      unsigned int v3 = g1[(size_t)s3 * 64 + lane];
      if (GDIS) {
        float d0 = __shfl(dsv, jx, 64);
        float d1 = __shfl(dsv, jx + 1, 64);
        float d2 = __shfl(dsv, jx + 2, 64);
        float d3 = __shfl(dsv, jx + 3, 64);
        ax = fmaf(d0, bf_lo(v0), ax);
        ay = fmaf(d0, bf_hi(v0), ay);
        ax = fmaf(d1, bf_lo(v1), ax);
        ay = fmaf(d1, bf_hi(v1), ay);
        ax = fmaf(d2, bf_lo(v2), ax);
        ay = fmaf(d2, bf_hi(v2), ay);
        ax = fmaf(d3, bf_lo(v3), ax);
        ay = fmaf(d3, bf_hi(v3), ay);
      } else {
        ax += (bf_lo(v0) + bf_lo(v1)) + (bf_lo(v2) + bf_lo(v3));
        ay += (bf_hi(v0) + bf_hi(v1)) + (bf_hi(v2) + bf_hi(v3));
      }
    }
    for (; jx < n; ++jx) {
      int s0 = __shfl(idx, jx, 64);
      unsigned int v = g1[(size_t)s0 * 64 + lane];
      if (GDIS) {
        float d0 = __shfl(dsv, jx, 64);
        ax = fmaf(d0, bf_lo(v), ax);
        ay = fmaf(d0, bf_hi(v), ay);
      } else {
        ax += bf_lo(v);
        ay += bf_hi(v);
      }
    }
  }
  float2 b = ((const float2*)bias)[lane];
  float rx = fmaxf(fmaf(di, ax, b.x), 0.f);
  float ry = fmaxf(fmaf(di, ay, b.y), 0.f);
  ushort2 o;
  o.x = f2bf(rx);
  o.y = f2bf(ry);
  ((ushort2*)outh)[(size_t)wid * 64 + lane] = o;
}

// ---------------- launch ----------------

extern "C" void kernel_launch(void* const* d_in, const int* in_sizes, int n_in,
                              void* d_out, int out_size, void* d_ws, size_t ws_size,
                              hipStream_t stream) {
  const float* x = (const float*)d_in[0];
  const int* ei = (const int*)d_in[1];
  const float* W1 = (const float*)d_in[2];
  const float* b1 = (const float*)d_in[3];
  const float* W2 = (const float*)d_in[4];
  const float* b2 = (const float*)d_in[5];
  const float* W3 = (const float*)d_in[6];
  const float* b3 = (const float*)d_in[7];
  const float* Wo1 = (const float*)d_in[8];
  const float* bo1 = (const float*)d_in[9];
  const float* Wo2 = (const float*)d_in[10];
  const float* bo2 = (const float*)d_in[11];
  float* out = (float*)d_out;

  int M = in_sizes[0] / DHID;  // 50000
  int E = in_sizes[1] / 2;     // 800000

  int NPB = (M + NBUK - 1) / NBUK;  // nodes per bucket (196)
  int EPB = (E + NBLK - 1) / NBLK;  // edges per sort block
  int SCN = NBUK * NBLK;            // 50176

  // workspace layout (~54.1 MB peak). Weights at 4MiB+64KB — csr spans
  // [5MiB, 8.45MiB) and must NOT touch them (round-7 NaN bug).
  char* ws = (char*)d_ws;
  float* dis = (float*)(ws + 0);                        // M floats (200KB)
  int* rp = (int*)(ws + (1ull << 20));                  // M+1 ints
  int* Hist = (int*)(ws + (2ull << 20));                // SCN ints (200KB)
  int* S = (int*)(ws + (3ull << 20));                   // SCN ints
  int* blk = (int*)(ws + (4ull << 20));                 // <=256 ints (1KB)
  unsigned short* W1t = (unsigned short*)(ws + (4ull << 20) + 65536 + 0 * 32768);
  unsigned short* W2t = (unsigned short*)(ws + (4ull << 20) + 65536 + 1 * 32768);
  unsigned short* W3t = (unsigned short*)(ws + (4ull << 20) + 65536 + 2 * 32768);
  unsigned short* Wo1t = (unsigned short*)(ws + (4ull << 20) + 65536 + 3 * 32768);
  unsigned short* Wo2t = (unsigned short*)(ws + (4ull << 20) + 65536 + 4 * 32768);
  // weights end at 4MiB+64KB+160KB = 4,423,680 < 5MiB ✓
  int* csr = (int*)(ws + (5ull << 20));                 // E ints: [5MiB, 8.45MiB)
  unsigned short* gA = (unsigned short*)(ws + (9ull << 20));   // M*128 bf16
  unsigned short* gB = (unsigned short*)(ws + (22ull << 20));  // M*128 bf16
  unsigned short* hb = (unsigned short*)(ws + (35ull << 20));  // M*128 bf16
  int2* sorted = (int2*)(ws + (48ull << 20));           // E int2 (6.4 MB)

  int gG = (M + 63) / 64;  // 782
  int gA4 = (M + 3) / 4;   // agg: 4 waves/block, wave per node

  // weight prep (bf16 transpose), then layer-1 GEMM fused with sort pass 1
  k_prep<<<40, 256, 0, stream>>>(W1, W2, W3, Wo1, Wo2, W1t, W2t, W3t, Wo1t, Wo2t);
  k_gemm1_hist<<<gG + NBLK, 256, 0, stream>>>(x, W1t, gA, M, gG, ei, E, EPB, NPB, Hist);
  // scan Hist (block totals scanned locally by scatter/finalize)
  k_scan1<<<NBLK, 256, 0, stream>>>(Hist, S, blk, SCN);
  // sort pass 2 + 3
  k_scatter<<<NBLK, 256, 0, stream>>>(ei, E, EPB, NPB, S, blk, sorted);
  k_finalize<<<NBUK, 256, 0, stream>>>(sorted, S, blk, E, M, NPB, rp, dis, csr);

  // GCN layers: agg (layer1 gathers dis) -> dis-scaled MFMA gemms
  k_agg<1><<<gA4, 256, 0, stream>>>(gA, csr, rp, dis, b1, hb, M);
  k_mgemm<128, 0, 3><<<gG, 256, 0, stream>>>(hb, W2t, nullptr, dis, gB, M);
  k_agg<0><<<gA4, 256, 0, stream>>>(gB, csr, rp, dis, b2, hb, M);
  k_mgemm<128, 0, 3><<<gG, 256, 0, stream>>>(hb, W3t, nullptr, dis, gA, M);
  k_agg<0><<<gA4, 256, 0, stream>>>(gA, csr, rp, dis, b3, hb, M);
  // fused MLP head
  k_mgemm2<<<gG, 256, 0, stream>>>(hb, Wo1t, bo1, Wo2t, bo2, out, M);
}